// Round 17
// baseline (296.597 us; speedup 1.0000x reference)
//
#include <hip/hip_runtime.h>
#include <math.h>

#define BB   64
#define CC   512
#define P2   49
#define CB   128
#define NB   3136   // BB * P2
#define TEMPI (1.0f/40.0f)

typedef __attribute__((ext_vector_type(4))) short    bf16x4;
typedef __attribute__((ext_vector_type(4))) float    f32x4;
typedef unsigned short u16;

__device__ inline u16 f2bf(float f) {
    union { float f; unsigned u; } x{f};
    unsigned r = (x.u + 0x7FFFu + ((x.u >> 16) & 1u)) >> 16;
    return (u16)r;
}

// Verified operand rule (derived from passing QK/PV/fusion kernels):
//   a: A[m = l&15][k = (l>>4)*4+j]
//   b: B[k = (l>>4)*4+j][n = l&15]
//   d: D[m = (l>>4)*4+r][n = l&15]
__device__ inline f32x4 mfma16x16(bf16x4 a, bf16x4 b, f32x4 c) {
#if __has_builtin(__builtin_amdgcn_mfma_f32_16x16x16bf16_1k)
    return __builtin_amdgcn_mfma_f32_16x16x16bf16_1k(a, b, c, 0, 0, 0);
#elif __has_builtin(__builtin_amdgcn_mfma_f32_16x16x16_bf16)
    return __builtin_amdgcn_mfma_f32_16x16x16_bf16(a, b, c, 0, 0, 0);
#else
    f32x4 d;
    asm("v_mfma_f32_16x16x16_bf16 %0, %1, %2, %3"
        : "=v"(d) : "v"(a), "v"(b), "v"(c));
    return d;
#endif
}

// ---------------------------------------------------------------------------
// 1) repack_all: Wq, Wk (512x512), Wf0 (128x512), Wf1 (512x128) into
//    B-operand fragments; Wkern (49x49) zero-padded to 64x64.
// ---------------------------------------------------------------------------
__global__ __launch_bounds__(256) void repack_all_k(
    const float* __restrict__ Wq, const float* __restrict__ Wk,
    const float* __restrict__ Wf0, const float* __restrict__ Wf1,
    const float* __restrict__ Wkern,
    u16* __restrict__ WqF, u16* __restrict__ WkF,
    u16* __restrict__ Wf0F, u16* __restrict__ Wf1F,
    u16* __restrict__ WkernF)
{
    int u = blockIdx.x * 256 + threadIdx.x;
    if (u >= 163840) {                      // Wkern, zero-padded
        int uu = u - 163840;
        int l = uu & 63, rest = uu >> 6;
        int ct = rest & 3, t = rest >> 2;
        int o  = t * 16 + (l & 15);
        int c0 = ct * 16 + ((l >> 4) << 2);
        ushort4 v;
        v.x = (o < 49 && c0 + 0 < 49) ? f2bf(Wkern[o * 49 + c0 + 0]) : 0;
        v.y = (o < 49 && c0 + 1 < 49) ? f2bf(Wkern[o * 49 + c0 + 1]) : 0;
        v.z = (o < 49 && c0 + 2 < 49) ? f2bf(Wkern[o * 49 + c0 + 2]) : 0;
        v.w = (o < 49 && c0 + 3 < 49) ? f2bf(Wkern[o * 49 + c0 + 3]) : 0;
        ((ushort4*)WkernF)[uu] = v;
        return;
    }
    const float* W; u16* dst; int K, uu;
    if (u < 65536)       { W = Wq;  dst = WqF;  K = 512; uu = u; }
    else if (u < 131072) { W = Wk;  dst = WkF;  K = 512; uu = u - 65536; }
    else if (u < 147456) { W = Wf0; dst = Wf0F; K = 512; uu = u - 131072; }
    else                 { W = Wf1; dst = Wf1F; K = 128; uu = u - 147456; }
    int l = uu & 63, rest = uu >> 6;
    int KT = K >> 4;
    int ct = rest % KT, t = rest / KT;
    int o  = t * 16 + (l & 15);
    int c0 = ct * 16 + ((l >> 4) << 2);
    float4 v = *(const float4*)(W + (size_t)o * K + c0);
    ushort4 w;
    w.x = f2bf(v.x); w.y = f2bf(v.y); w.z = f2bf(v.z); w.w = f2bf(v.w);
    ((ushort4*)dst)[uu] = w;
}

// ---------------------------------------------------------------------------
// 2) prep: pool+BN -> LDS pf[32][50]; emit pfF fragments and VF via MFMA.
// ---------------------------------------------------------------------------
__global__ __launch_bounds__(256) void prep_k(
    const float* __restrict__ x, const float* __restrict__ g,
    const float* __restrict__ be, const float* __restrict__ mu,
    const float* __restrict__ var, const u16* __restrict__ WkernF,
    u16* __restrict__ pfF, u16* __restrict__ VF)
{
    __shared__ float pf[32][50];
    int tid = threadIdx.x;
    int bg  = blockIdx.x;          // b*16 + grp
    int b = bg >> 4, grp = bg & 15;
    int cbase = grp * 32;

    for (int i = tid; i < 32 * 49; i += 256) {
        int cl = i / 49, p = i - cl * 49;
        int c = cbase + cl;
        const float* basep = x + ((size_t)(b * 512 + c)) * 784
                             + (p / 7) * 4 * 28 + (p % 7) * 4;
        float s = 0.f;
#pragma unroll
        for (int r = 0; r < 4; ++r) {
            float4 v = *(const float4*)(basep + r * 28);
            s += v.x + v.y + v.z + v.w;
        }
        s *= (1.f / 16.f);
        float sc = g[c] * rsqrtf(var[c] + 1e-5f);
        pf[cl][p] = (s - mu[c]) * sc + be[c];
    }
    __syncthreads();

    for (int u = tid; u < 512; u += 256) {
        int l = u & 63, q = (u >> 6) & 3, ctl = u >> 8;     // ctl 0..1
        int p   = q * 16 + (l & 15);
        int c0l = ctl * 16 + ((l >> 4) << 2);
        ushort4 o;
        if (p < 49) {
            o.x = f2bf(pf[c0l + 0][p]); o.y = f2bf(pf[c0l + 1][p]);
            o.z = f2bf(pf[c0l + 2][p]); o.w = f2bf(pf[c0l + 3][p]);
        } else { o.x = o.y = o.z = o.w = 0; }
        ((ushort4*)pfF)[((size_t)(b * 32 + grp * 2 + ctl) * 4 + q) * 64 + l] = o;
    }

    int lane = tid & 63, w = tid >> 6;
    const bf16x4* WkF4 = (const bf16x4*)WkernF;
#pragma unroll
    for (int i = 0; i < 2; ++i) {
        int dt  = w * 2 + i;           // 0..7
        int ct2 = dt & 1, tk = dt >> 1;
        int cc  = ct2 * 16 + (lane & 15);
        f32x4 acc = (f32x4)0.f;
#pragma unroll
        for (int ptp = 0; ptp < 4; ++ptp) {
            bf16x4 af;
#pragma unroll
            for (int j = 0; j < 4; ++j) {
                int p = ptp * 16 + ((lane >> 4) << 2) + j;
                af[j] = (short)((p < 49) ? f2bf(pf[cc][p]) : 0);
            }
            bf16x4 bw = WkF4[(tk * 4 + ptp) * 64 + lane];
            acc = mfma16x16(af, bw, acc);
        }
        ushort4 o;
        o.x = f2bf(acc[0]); o.y = f2bf(acc[1]);
        o.z = f2bf(acc[2]); o.w = f2bf(acc[3]);
        ((ushort4*)VF)[((size_t)(b * 32 + grp * 2 + ct2) * 4 + tk) * 64 + lane] = o;
    }
}

// ---------------------------------------------------------------------------
// 3) MEGA kernel: one block per batch b (64 blocks x 512 threads = 8 waves).
//    Phases: QK GEMMs -> attention -> fusion0+LN+tanh -> fusion1, separated
//    by __syncthreads (drains vmcnt; same-CU L1 is write-through so the
//    block-private global scratch QF/KF/OtF is coherent across waves).
//    GF lives in LDS. All fragment maps are verbatim ports of the verified
//    round-13/15 kernels; only wave->tile assignments changed (4 tiles/wave).
// ---------------------------------------------------------------------------
__global__ __launch_bounds__(512) void mega_k(
    const u16* __restrict__ pfF, const u16* __restrict__ WqF,
    const u16* __restrict__ WkF, u16* __restrict__ QF, u16* __restrict__ KF,
    const u16* __restrict__ VF, u16* __restrict__ OtF,
    const u16* __restrict__ Wf0F, const float* __restrict__ bf0,
    const float* __restrict__ lnw, const float* __restrict__ lnb,
    const u16* __restrict__ Wf1F, const float* __restrict__ bf1,
    float* __restrict__ KernT)
{
    __shared__ float F0[128][50];          // 25.6 KB
    __shared__ ushort4 GfLds[32][64];      // 16 KB
    __shared__ float rs[8], rq[8];
    __shared__ float smu, srstd;

    int tid  = threadIdx.x;
    int lane = tid & 63, w = tid >> 6;     // 8 waves
    int b    = blockIdx.x;

    // ---------------- phase 1: Q and K fragment GEMMs ----------------
    {
        const bf16x4* Ab = (const bf16x4*)pfF + (size_t)b * 8192 + lane;
#pragma unroll
        for (int z = 0; z < 2; ++z) {
            const u16* WF = z ? WkF : WqF;
            u16* dstF = z ? KF : QF;
#pragma unroll
            for (int i = 0; i < 4; ++i) {
                int t = w + 8 * i;
                const bf16x4* Bw = (const bf16x4*)WF + (size_t)t * 2048 + lane;
                f32x4 acc[4];
#pragma unroll
                for (int q = 0; q < 4; ++q) acc[q] = (f32x4)0.f;
#pragma unroll
                for (int ct = 0; ct < 32; ++ct) {
                    bf16x4 wv = Bw[ct * 64];
                    bf16x4 a0 = Ab[(ct * 4 + 0) * 64];
                    bf16x4 a1 = Ab[(ct * 4 + 1) * 64];
                    bf16x4 a2 = Ab[(ct * 4 + 2) * 64];
                    bf16x4 a3 = Ab[(ct * 4 + 3) * 64];
                    acc[0] = mfma16x16(a0, wv, acc[0]);
                    acc[1] = mfma16x16(a1, wv, acc[1]);
                    acc[2] = mfma16x16(a2, wv, acc[2]);
                    acc[3] = mfma16x16(a3, wv, acc[3]);
                }
#pragma unroll
                for (int q = 0; q < 4; ++q) {
                    ushort4 u;
                    u.x = f2bf(acc[q][0]); u.y = f2bf(acc[q][1]);
                    u.z = f2bf(acc[q][2]); u.w = f2bf(acc[q][3]);
                    ((ushort4*)dstF)[(((size_t)b * 32 + t) * 4 + q) * 64 + lane] = u;
                }
            }
        }
    }
    __syncthreads();

    // ---------------- phase 2: attention (verbatim round-13 body) ----------------
    {
        const bf16x4* KFp = (const bf16x4*)KF + (size_t)b * 8192 + lane;
        const bf16x4* VFp = (const bf16x4*)VF + (size_t)b * 8192 + lane;
#pragma unroll
        for (int i = 0; i < 4; ++i) {
            int ct = w + 8 * i;
            const bf16x4* QFp = (const bf16x4*)QF + (size_t)b * 8192 + ct * 256 + lane;

            bf16x4 qf[4];
#pragma unroll
            for (int q = 0; q < 4; ++q) qf[q] = QFp[q * 64];

            f32x4 o[4];
#pragma unroll
            for (int pt = 0; pt < 4; ++pt) o[pt] = (f32x4)0.f;
            float lsum = 0.f;

            bf16x4 kf[4], vf[4], kn[4], vn[4];
#pragma unroll
            for (int q = 0; q < 4; ++q) { kf[q] = KFp[q * 64]; vf[q] = VFp[q * 64]; }

            for (int t = 0; t < 32; ++t) {
                if (t < 31) {
                    const bf16x4* kp = KFp + (t + 1) * 256;
                    const bf16x4* vp = VFp + (t + 1) * 256;
#pragma unroll
                    for (int q = 0; q < 4; ++q) { kn[q] = kp[q * 64]; vn[q] = vp[q * 64]; }
                }
                f32x4 s = (f32x4)0.f;
#pragma unroll
                for (int q = 0; q < 4; ++q) s = mfma16x16(kf[q], qf[q], s);

                bf16x4 pa;
#pragma unroll
                for (int r = 0; r < 4; ++r) {
                    float pe = __expf(s[r] * TEMPI);
                    lsum += pe;
                    pa[r] = (short)f2bf(pe);
                }
#pragma unroll
                for (int pt = 0; pt < 4; ++pt) o[pt] = mfma16x16(pa, vf[pt], o[pt]);

#pragma unroll
                for (int q = 0; q < 4; ++q) { kf[q] = kn[q]; vf[q] = vn[q]; }
            }

            lsum += __shfl_xor(lsum, 16);
            lsum += __shfl_xor(lsum, 32);
            float linv = 1.f / lsum;

            int g4 = (lane >> 4) << 2;
            float rl0 = __shfl(linv, g4 + 0);
            float rl1 = __shfl(linv, g4 + 1);
            float rl2 = __shfl(linv, g4 + 2);
            float rl3 = __shfl(linv, g4 + 3);

#pragma unroll
            for (int pt = 0; pt < 4; ++pt) {
                ushort4 u;
                u.x = f2bf(o[pt][0] * rl0);
                u.y = f2bf(o[pt][1] * rl1);
                u.z = f2bf(o[pt][2] * rl2);
                u.w = f2bf(o[pt][3] * rl3);
                ((ushort4*)OtF)[(((size_t)b * 32 + ct) * 4 + pt) * 64 + lane] = u;
            }
        }
    }
    __syncthreads();

    // ---------------- phase 3: fusion0 + LayerNorm + tanh (verbatim f0ln) ----
    {
        const bf16x4* Ab = (const bf16x4*)OtF + (size_t)b * 8192 + lane;
        const bf16x4* Bw = (const bf16x4*)Wf0F + (size_t)w * 2048 + lane;

        f32x4 acc[4];
#pragma unroll
        for (int q = 0; q < 4; ++q) acc[q] = (f32x4)0.f;
#pragma unroll
        for (int ct = 0; ct < 32; ++ct) {
            bf16x4 wv = Bw[ct * 64];
            bf16x4 a0 = Ab[(ct * 4 + 0) * 64];
            bf16x4 a1 = Ab[(ct * 4 + 1) * 64];
            bf16x4 a2 = Ab[(ct * 4 + 2) * 64];
            bf16x4 a3 = Ab[(ct * 4 + 3) * 64];
            acc[0] = mfma16x16(a0, wv, acc[0]);
            acc[1] = mfma16x16(a1, wv, acc[1]);
            acc[2] = mfma16x16(a2, wv, acc[2]);
            acc[3] = mfma16x16(a3, wv, acc[3]);
        }

        int c = w * 16 + (lane & 15);
        float bb = bf0[c];
        int g4 = (lane >> 4) << 2;
#pragma unroll
        for (int q = 0; q < 4; ++q)
#pragma unroll
            for (int r = 0; r < 4; ++r) {
                int p = q * 16 + g4 + r;
                if (p < 49) F0[c][p] = acc[q][r] + bb;
            }
        __syncthreads();

        float s = 0.f, sq = 0.f;
        for (int e = tid; e < CB * 49; e += 512) {
            int o = e / 49, k = e - o * 49;
            float v = F0[o][k];
            s += v; sq += v * v;
        }
#pragma unroll
        for (int off = 32; off > 0; off >>= 1) {
            s  += __shfl_xor(s, off);
            sq += __shfl_xor(sq, off);
        }
        if ((tid & 63) == 0) { rs[w] = s; rq[w] = sq; }
        __syncthreads();
        if (tid == 0) {
            float S = 0.f, Q = 0.f;
#pragma unroll
            for (int i = 0; i < 8; ++i) { S += rs[i]; Q += rq[i]; }
            float mu = S / 6272.f;
            float v  = Q / 6272.f - mu * mu;
            smu = mu; srstd = rsqrtf(v + 1e-5f);
        }
        __syncthreads();
        float mu = smu, rstd = srstd;

        for (int u = tid; u < 2048; u += 512) {
            int l = u & 63, q = (u >> 6) & 3, ct = u >> 8;
            int c0 = ct * 16 + ((l >> 4) << 2);
            int k  = q * 16 + (l & 15);
            ushort4 o;
            if (k < 49) {
                o.x = f2bf(tanhf((F0[c0+0][k] - mu) * rstd * lnw[(c0+0)*49+k] + lnb[(c0+0)*49+k]));
                o.y = f2bf(tanhf((F0[c0+1][k] - mu) * rstd * lnw[(c0+1)*49+k] + lnb[(c0+1)*49+k]));
                o.z = f2bf(tanhf((F0[c0+2][k] - mu) * rstd * lnw[(c0+2)*49+k] + lnb[(c0+2)*49+k]));
                o.w = f2bf(tanhf((F0[c0+3][k] - mu) * rstd * lnw[(c0+3)*49+k] + lnb[(c0+3)*49+k]));
            } else { o.x = o.y = o.z = o.w = 0; }
            GfLds[ct * 4 + q][l] = o;
        }
    }
    __syncthreads();

    // ---------------- phase 4: fusion1 (KT=8, reads GfLds) ----------------
    {
#pragma unroll
        for (int i = 0; i < 4; ++i) {
            int t = w + 8 * i;
            const bf16x4* Bw = (const bf16x4*)Wf1F + (size_t)t * 512 + lane;

            f32x4 acc[4];
#pragma unroll
            for (int q = 0; q < 4; ++q) acc[q] = (f32x4)0.f;
#pragma unroll
            for (int ct = 0; ct < 8; ++ct) {
                bf16x4 wv = Bw[ct * 64];
                bf16x4 a0 = *(bf16x4*)&GfLds[ct * 4 + 0][lane];
                bf16x4 a1 = *(bf16x4*)&GfLds[ct * 4 + 1][lane];
                bf16x4 a2 = *(bf16x4*)&GfLds[ct * 4 + 2][lane];
                bf16x4 a3 = *(bf16x4*)&GfLds[ct * 4 + 3][lane];
                acc[0] = mfma16x16(a0, wv, acc[0]);
                acc[1] = mfma16x16(a1, wv, acc[1]);
                acc[2] = mfma16x16(a2, wv, acc[2]);
                acc[3] = mfma16x16(a3, wv, acc[3]);
            }

            int c = t * 16 + (lane & 15);
            float bb = bf1[c];
            float* op = KernT + (size_t)c * NB + b * 49;
            int g4 = (lane >> 4) << 2;
#pragma unroll
            for (int q = 0; q < 4; ++q) {
#pragma unroll
                for (int r = 0; r < 4; ++r) {
                    int p = q * 16 + g4 + r;
                    if (p < 49) op[p] = acc[q][r] + bb;
                }
            }
        }
    }
}

// ---------------------------------------------------------------------------
// 4) dynamic depthwise 7x7 conv (round-8/13 best: wave-per-plane, SGPR
//    weights, skewed LDS staging).
// ---------------------------------------------------------------------------
#define PLS 1256
__global__ __launch_bounds__(256) void dwconv_k(
    const float* __restrict__ x, const float* __restrict__ KernT,
    float* __restrict__ out)
{
    __shared__ float xs[4 * PLS];
    int tid  = threadIdx.x;
    int lane = tid & 63;
    int wid  = tid >> 6;
    int P    = blockIdx.x * 4 + wid;
    int b = P >> 9, c = P & 511;
    float* pl = &xs[wid * PLS];

    float4* plf = (float4*)pl;
#pragma unroll
    for (int r = 0; r < 5; ++r) {
        int l = lane + 64 * r;
        if (l < PLS / 4) plf[l] = float4{0.f, 0.f, 0.f, 0.f};
    }

    float wvl = 0.f;
    if (lane < 49) wvl = KernT[(size_t)c * NB + b * 49 + lane];
    int wvi = __float_as_int(wvl);
    float w[49];
#pragma unroll
    for (int i = 0; i < 49; ++i)
        w[i] = __int_as_float(__builtin_amdgcn_readlane(wvi, i));

    const float* src = x + (size_t)P * 784;
#pragma unroll
    for (int r = 0; r < 4; ++r) {
        int q = lane + 64 * r;
        if (q < 196) {
            int y = q / 7, xq = 4 * (q % 7);
            int R = y + 3;
            *(float4*)&pl[R * 36 + (((R >> 2) & 7) << 2) + xq + 4] =
                *(const float4*)(src + y * 28 + xq);
        }
    }

    if (lane >= 49) return;
    int ty = lane / 7, gx = lane - ty * 7;
    int y0 = 4 * ty, x0 = 4 * gx;
    float acc[4][4] = {};

#pragma unroll
    for (int yy = 0; yy < 10; ++yy) {
        int R = y0 + yy;
        const float* rp = &pl[R * 36 + (((R >> 2) & 7) << 2) + x0];
        float4 fa = *(const float4*)(rp);
        float4 fb = *(const float4*)(rp + 4);
        float4 fc = *(const float4*)(rp + 8);
        float f[12] = {fa.x, fa.y, fa.z, fa.w, fb.x, fb.y, fb.z, fb.w,
                       fc.x, fc.y, fc.z, fc.w};
#pragma unroll
        for (int j = 0; j < 4; ++j) {
            int dy = yy - j;
            if (dy < 0 || dy > 6) continue;
#pragma unroll
            for (int dx = 0; dx < 7; ++dx) {
                float wv = w[dy * 7 + dx];
                acc[j][0] = fmaf(wv, f[dx + 1], acc[j][0]);
                acc[j][1] = fmaf(wv, f[dx + 2], acc[j][1]);
                acc[j][2] = fmaf(wv, f[dx + 3], acc[j][2]);
                acc[j][3] = fmaf(wv, f[dx + 4], acc[j][3]);
            }
        }
    }

    float* op = out + (size_t)P * 784;
#pragma unroll
    for (int j = 0; j < 4; ++j) {
        float4 o4 = {acc[j][0], acc[j][1], acc[j][2], acc[j][3]};
        *(float4*)(op + (y0 + j) * 28 + x0) = o4;
    }
}

// ---------------------------------------------------------------------------
extern "C" void kernel_launch(void* const* d_in, const int* in_sizes, int n_in,
                              void* d_out, int out_size, void* d_ws, size_t ws_size,
                              hipStream_t stream)
{
    const float* x     = (const float*)d_in[0];
    const float* bng   = (const float*)d_in[1];
    const float* bnb   = (const float*)d_in[2];
    const float* bnm   = (const float*)d_in[3];
    const float* bnv   = (const float*)d_in[4];
    const float* Wq    = (const float*)d_in[5];
    const float* Wk    = (const float*)d_in[6];
    const float* Wkern = (const float*)d_in[7];
    const float* Wf0   = (const float*)d_in[8];
    const float* bf0   = (const float*)d_in[9];
    const float* lnw   = (const float*)d_in[10];
    const float* lnb   = (const float*)d_in[11];
    const float* Wf1   = (const float*)d_in[12];
    const float* bf1   = (const float*)d_in[13];
    float* out = (float*)d_out;
    float* ws  = (float*)d_ws;

    // workspace (float-equiv offsets), peak 7,178,240 f = 28.7 MB
    // (proven available: round-1 map used 33.7 MB)
    u16* pfF    = (u16*)(ws + 0);            // [0 .. 1,048,576)
    u16* VF     = (u16*)(ws + 1048576);      // [1,048,576 .. 2,097,152)
    u16* WqF    = (u16*)(ws + 2097152);      // [2,097,152 .. 2,228,224)
    u16* WkF    = (u16*)(ws + 2228224);      // [2,228,224 .. 2,359,296)
    u16* Wf0F   = (u16*)(ws + 2359296);      // [2,359,296 .. 2,392,064)
    u16* Wf1F   = (u16*)(ws + 2392064);      // [2,392,064 .. 2,424,832)
    u16* WkernF = (u16*)(ws + 2424832);      // [2,424,832 .. 2,426,880)
    u16* QF     = (u16*)(ws + 2426880);      // [2,426,880 .. 3,475,456)
    u16* KF     = (u16*)(ws + 3475456);      // [3,475,456 .. 4,524,032)
    u16* OtF    = (u16*)(ws + 4524032);      // [4,524,032 .. 5,572,608)
    float* KernT = ws + 5572608;             // [5,572,608 .. 7,178,240)
    // NOTE: KernT no longer aliases QF/KF -- in the fused kernel, block b's
    // fusion1 writes span all channels while other blocks still read QF/KF.

    repack_all_k<<<644, 256, 0, stream>>>(Wq, Wk, Wf0, Wf1, Wkern,
                                          WqF, WkF, Wf0F, Wf1F, WkernF);
    prep_k<<<1024, 256, 0, stream>>>(x, bng, bnb, bnm, bnv, WkernF, pfF, VF);
    mega_k<<<64, 512, 0, stream>>>(pfF, WqF, WkF, QF, KF, VF, OtF,
                                   Wf0F, bf0, lnw, lnb, Wf1F, bf1, KernT);
    dwconv_k<<<8192, 256, 0, stream>>>(x, KernT, out);
}

// Round 18
// 159.164 us; speedup vs baseline: 1.8635x; 1.8635x over previous
//
#include <hip/hip_runtime.h>
#include <math.h>

#define BB   64
#define CC   512
#define P2   49
#define CB   128
#define NB   3136   // BB * P2
#define TEMPI (1.0f/40.0f)

typedef __attribute__((ext_vector_type(4))) short    bf16x4;
typedef __attribute__((ext_vector_type(4))) float    f32x4;
typedef unsigned short u16;

__device__ inline u16 f2bf(float f) {
    union { float f; unsigned u; } x{f};
    unsigned r = (x.u + 0x7FFFu + ((x.u >> 16) & 1u)) >> 16;
    return (u16)r;
}

// Verified operand rule (derived from passing QK/PV/fusion kernels):
//   a: A[m = l&15][k = (l>>4)*4+j]
//   b: B[k = (l>>4)*4+j][n = l&15]
//   d: D[m = (l>>4)*4+r][n = l&15]
__device__ inline f32x4 mfma16x16(bf16x4 a, bf16x4 b, f32x4 c) {
#if __has_builtin(__builtin_amdgcn_mfma_f32_16x16x16bf16_1k)
    return __builtin_amdgcn_mfma_f32_16x16x16bf16_1k(a, b, c, 0, 0, 0);
#elif __has_builtin(__builtin_amdgcn_mfma_f32_16x16x16_bf16)
    return __builtin_amdgcn_mfma_f32_16x16x16_bf16(a, b, c, 0, 0, 0);
#else
    f32x4 d;
    asm("v_mfma_f32_16x16x16_bf16 %0, %1, %2, %3"
        : "=v"(d) : "v"(a), "v"(b), "v"(c));
    return d;
#endif
}

// ---------------------------------------------------------------------------
// 1) repack_all: Wq, Wk (512x512), Wf0 (128x512), Wf1 (512x128) into
//    B-operand fragments; Wkern (49x49) zero-padded to 64x64.
// ---------------------------------------------------------------------------
__global__ __launch_bounds__(256) void repack_all_k(
    const float* __restrict__ Wq, const float* __restrict__ Wk,
    const float* __restrict__ Wf0, const float* __restrict__ Wf1,
    const float* __restrict__ Wkern,
    u16* __restrict__ WqF, u16* __restrict__ WkF,
    u16* __restrict__ Wf0F, u16* __restrict__ Wf1F,
    u16* __restrict__ WkernF)
{
    int u = blockIdx.x * 256 + threadIdx.x;
    if (u >= 163840) {                      // Wkern, zero-padded
        int uu = u - 163840;
        int l = uu & 63, rest = uu >> 6;
        int ct = rest & 3, t = rest >> 2;
        int o  = t * 16 + (l & 15);
        int c0 = ct * 16 + ((l >> 4) << 2);
        ushort4 v;
        v.x = (o < 49 && c0 + 0 < 49) ? f2bf(Wkern[o * 49 + c0 + 0]) : 0;
        v.y = (o < 49 && c0 + 1 < 49) ? f2bf(Wkern[o * 49 + c0 + 1]) : 0;
        v.z = (o < 49 && c0 + 2 < 49) ? f2bf(Wkern[o * 49 + c0 + 2]) : 0;
        v.w = (o < 49 && c0 + 3 < 49) ? f2bf(Wkern[o * 49 + c0 + 3]) : 0;
        ((ushort4*)WkernF)[uu] = v;
        return;
    }
    const float* W; u16* dst; int K, uu;
    if (u < 65536)       { W = Wq;  dst = WqF;  K = 512; uu = u; }
    else if (u < 131072) { W = Wk;  dst = WkF;  K = 512; uu = u - 65536; }
    else if (u < 147456) { W = Wf0; dst = Wf0F; K = 512; uu = u - 131072; }
    else                 { W = Wf1; dst = Wf1F; K = 128; uu = u - 147456; }
    int l = uu & 63, rest = uu >> 6;
    int KT = K >> 4;
    int ct = rest % KT, t = rest / KT;
    int o  = t * 16 + (l & 15);
    int c0 = ct * 16 + ((l >> 4) << 2);
    float4 v = *(const float4*)(W + (size_t)o * K + c0);
    ushort4 w;
    w.x = f2bf(v.x); w.y = f2bf(v.y); w.z = f2bf(v.z); w.w = f2bf(v.w);
    ((ushort4*)dst)[uu] = w;
}

// ---------------------------------------------------------------------------
// 2) prep: pool+BN -> LDS pf[128][50]; emit pfF fragments and VF via MFMA
//    (A = pf-frag, B = WkernF -- verified orientation). Grid 256.
// ---------------------------------------------------------------------------
__global__ __launch_bounds__(256) void prep_k(
    const float* __restrict__ x, const float* __restrict__ g,
    const float* __restrict__ be, const float* __restrict__ mu,
    const float* __restrict__ var, const u16* __restrict__ WkernF,
    u16* __restrict__ pfF, u16* __restrict__ VF)
{
    __shared__ float pf[128][50];
    int tid = threadIdx.x;
    int bg  = blockIdx.x;          // b*4 + grp
    int b = bg >> 2, grp = bg & 3;
    int cbase = grp * 128;

    // stage 1: pool + BN
    for (int i = tid; i < 128 * 49; i += 256) {
        int cl = i / 49, p = i - cl * 49;
        int c = cbase + cl;
        const float* basep = x + ((size_t)(b * 512 + c)) * 784
                             + (p / 7) * 4 * 28 + (p % 7) * 4;
        float s = 0.f;
#pragma unroll
        for (int r = 0; r < 4; ++r) {
            float4 v = *(const float4*)(basep + r * 28);
            s += v.x + v.y + v.z + v.w;
        }
        s *= (1.f / 16.f);
        float sc = g[c] * rsqrtf(var[c] + 1e-5f);
        pf[cl][p] = (s - mu[c]) * sc + be[c];
    }
    __syncthreads();

    // stage 2: pfF fragments (verbatim repack_pf map, 2048 units)
    for (int u = tid; u < 2048; u += 256) {
        int l = u & 63, q = (u >> 6) & 3, ctl = u >> 8;
        int p   = q * 16 + (l & 15);
        int c0l = ctl * 16 + ((l >> 4) << 2);
        ushort4 o;
        if (p < 49) {
            o.x = f2bf(pf[c0l + 0][p]); o.y = f2bf(pf[c0l + 1][p]);
            o.z = f2bf(pf[c0l + 2][p]); o.w = f2bf(pf[c0l + 3][p]);
        } else { o.x = o.y = o.z = o.w = 0; }
        ((ushort4*)pfF)[((size_t)(b * 32 + grp * 8 + ctl) * 4 + q) * 64 + l] = o;
    }

    // stage 3: VF via MFMA with pf as A-operand, WkernF as B-operand.
    int lane = tid & 63, w = tid >> 6;
    const bf16x4* WkF4 = (const bf16x4*)WkernF;
#pragma unroll
    for (int i = 0; i < 8; ++i) {
        int dt  = w * 8 + i;           // 32 D-tiles / 4 waves
        int ct2 = dt >> 2, tk = dt & 3;
        int cc  = ct2 * 16 + (lane & 15);   // channel from LO (A's m index)
        f32x4 acc = (f32x4)0.f;
#pragma unroll
        for (int ptp = 0; ptp < 4; ++ptp) {
            bf16x4 af;                       // A[m=cc][k=p via hi+j]
#pragma unroll
            for (int j = 0; j < 4; ++j) {
                int p = ptp * 16 + ((lane >> 4) << 2) + j;
                af[j] = (short)((p < 49) ? f2bf(pf[cc][p]) : 0);
            }
            bf16x4 bw = WkF4[(tk * 4 + ptp) * 64 + lane];  // B[k=p][n=kpos]
            acc = mfma16x16(af, bw, acc);
        }
        ushort4 o;
        o.x = f2bf(acc[0]); o.y = f2bf(acc[1]);
        o.z = f2bf(acc[2]); o.w = f2bf(acc[3]);
        ((ushort4*)VF)[((size_t)(b * 32 + grp * 8 + ct2) * 4 + tk) * 64 + lane] = o;
    }
}

// ---------------------------------------------------------------------------
// 3) Q and K fragment GEMMs in one launch (z selects Wq/Wk).
// ---------------------------------------------------------------------------
__global__ __launch_bounds__(256) void gemm_qk_k(
    const u16* __restrict__ pfF, const u16* __restrict__ WqF,
    const u16* __restrict__ WkF, u16* __restrict__ QF, u16* __restrict__ KF)
{
    const u16* WF   = blockIdx.z ? WkF : WqF;
    u16*       dstF = blockIdx.z ? KF : QF;
    int tid  = threadIdx.x;
    int lane = tid & 63;
    int w    = tid >> 6;
    int b    = blockIdx.y;
    int t    = blockIdx.x * 4 + w;

    const bf16x4* Ab = (const bf16x4*)pfF + (size_t)b * 8192 + lane;
    const bf16x4* Bw = (const bf16x4*)WF + (size_t)t * 2048 + lane;

    f32x4 acc[4];
#pragma unroll
    for (int q = 0; q < 4; ++q) acc[q] = (f32x4)0.f;

#pragma unroll
    for (int ct = 0; ct < 32; ++ct) {
        bf16x4 wv = Bw[ct * 64];
        bf16x4 a0 = Ab[(ct * 4 + 0) * 64];
        bf16x4 a1 = Ab[(ct * 4 + 1) * 64];
        bf16x4 a2 = Ab[(ct * 4 + 2) * 64];
        bf16x4 a3 = Ab[(ct * 4 + 3) * 64];
        acc[0] = mfma16x16(a0, wv, acc[0]);
        acc[1] = mfma16x16(a1, wv, acc[1]);
        acc[2] = mfma16x16(a2, wv, acc[2]);
        acc[3] = mfma16x16(a3, wv, acc[3]);
    }

#pragma unroll
    for (int q = 0; q < 4; ++q) {
        ushort4 u;
        u.x = f2bf(acc[q][0]); u.y = f2bf(acc[q][1]);
        u.z = f2bf(acc[q][2]); u.w = f2bf(acc[q][3]);
        ((ushort4*)dstF)[(((size_t)b * 32 + t) * 4 + q) * 64 + lane] = u;
    }
}

// ---------------------------------------------------------------------------
// 4) MFMA flash attention; output as bf16 A-fragments (verified).
// ---------------------------------------------------------------------------
__global__ __launch_bounds__(256) void attn_mfma_k(
    const u16* __restrict__ QF, const u16* __restrict__ KF,
    const u16* __restrict__ VF, u16* __restrict__ OtF)
{
    int tid  = threadIdx.x;
    int lane = tid & 63;
    int w    = tid >> 6;
    int b    = blockIdx.y;
    int ct   = blockIdx.x * 4 + w;

    const bf16x4* QFp = (const bf16x4*)QF + (size_t)b * 8192 + ct * 256 + lane;
    const bf16x4* KFp = (const bf16x4*)KF + (size_t)b * 8192 + lane;
    const bf16x4* VFp = (const bf16x4*)VF + (size_t)b * 8192 + lane;

    bf16x4 qf[4];
#pragma unroll
    for (int q = 0; q < 4; ++q) qf[q] = QFp[q * 64];

    f32x4 o[4];
#pragma unroll
    for (int pt = 0; pt < 4; ++pt) o[pt] = (f32x4)0.f;
    float lsum = 0.f;

    bf16x4 kf[4], vf[4], kn[4], vn[4];
#pragma unroll
    for (int q = 0; q < 4; ++q) { kf[q] = KFp[q * 64]; vf[q] = VFp[q * 64]; }

    for (int t = 0; t < 32; ++t) {
        if (t < 31) {
            const bf16x4* kp = KFp + (t + 1) * 256;
            const bf16x4* vp = VFp + (t + 1) * 256;
#pragma unroll
            for (int q = 0; q < 4; ++q) { kn[q] = kp[q * 64]; vn[q] = vp[q * 64]; }
        }
        f32x4 s = (f32x4)0.f;
#pragma unroll
        for (int q = 0; q < 4; ++q) s = mfma16x16(kf[q], qf[q], s);

        bf16x4 pa;
#pragma unroll
        for (int r = 0; r < 4; ++r) {
            float pe = __expf(s[r] * TEMPI);
            lsum += pe;
            pa[r] = (short)f2bf(pe);
        }
#pragma unroll
        for (int pt = 0; pt < 4; ++pt) o[pt] = mfma16x16(pa, vf[pt], o[pt]);

#pragma unroll
        for (int q = 0; q < 4; ++q) { kf[q] = kn[q]; vf[q] = vn[q]; }
    }

    lsum += __shfl_xor(lsum, 16);
    lsum += __shfl_xor(lsum, 32);
    float linv = 1.f / lsum;

    int g4 = (lane >> 4) << 2;
    float rl0 = __shfl(linv, g4 + 0);
    float rl1 = __shfl(linv, g4 + 1);
    float rl2 = __shfl(linv, g4 + 2);
    float rl3 = __shfl(linv, g4 + 3);

#pragma unroll
    for (int pt = 0; pt < 4; ++pt) {
        ushort4 u;
        u.x = f2bf(o[pt][0] * rl0);
        u.y = f2bf(o[pt][1] * rl1);
        u.z = f2bf(o[pt][2] * rl2);
        u.w = f2bf(o[pt][3] * rl3);
        ((ushort4*)OtF)[(((size_t)b * 32 + ct) * 4 + pt) * 64 + lane] = u;
    }
}

// ---------------------------------------------------------------------------
// 5) fusion0 + LayerNorm + tanh fused, per batch; 512 threads (wave w = t).
// ---------------------------------------------------------------------------
__global__ __launch_bounds__(512) void f0ln_k(
    const u16* __restrict__ OtF, const u16* __restrict__ Wf0F,
    const float* __restrict__ bf0, const float* __restrict__ lnw,
    const float* __restrict__ lnb, u16* __restrict__ GF)
{
    __shared__ float F0[128][50];
    __shared__ float rs[8], rq[8];
    __shared__ float smu, srstd;
    int tid  = threadIdx.x;
    int lane = tid & 63, w = tid >> 6;   // w = output c-tile 0..7
    int b = blockIdx.x;

    const bf16x4* Ab = (const bf16x4*)OtF + (size_t)b * 8192 + lane;
    const bf16x4* Bw = (const bf16x4*)Wf0F + (size_t)w * 2048 + lane;

    f32x4 acc[4];
#pragma unroll
    for (int q = 0; q < 4; ++q) acc[q] = (f32x4)0.f;
#pragma unroll
    for (int ct = 0; ct < 32; ++ct) {
        bf16x4 wv = Bw[ct * 64];
        bf16x4 a0 = Ab[(ct * 4 + 0) * 64];
        bf16x4 a1 = Ab[(ct * 4 + 1) * 64];
        bf16x4 a2 = Ab[(ct * 4 + 2) * 64];
        bf16x4 a3 = Ab[(ct * 4 + 3) * 64];
        acc[0] = mfma16x16(a0, wv, acc[0]);
        acc[1] = mfma16x16(a1, wv, acc[1]);
        acc[2] = mfma16x16(a2, wv, acc[2]);
        acc[3] = mfma16x16(a3, wv, acc[3]);
    }

    int c = w * 16 + (lane & 15);
    float bb = bf0[c];
    int g4 = (lane >> 4) << 2;
#pragma unroll
    for (int q = 0; q < 4; ++q)
#pragma unroll
        for (int r = 0; r < 4; ++r) {
            int p = q * 16 + g4 + r;
            if (p < 49) F0[c][p] = acc[q][r] + bb;
        }
    __syncthreads();

    float s = 0.f, sq = 0.f;
    for (int e = tid; e < CB * 49; e += 512) {
        int o = e / 49, k = e - o * 49;
        float v = F0[o][k];
        s += v; sq += v * v;
    }
#pragma unroll
    for (int off = 32; off > 0; off >>= 1) {
        s  += __shfl_xor(s, off);
        sq += __shfl_xor(sq, off);
    }
    if ((tid & 63) == 0) { rs[w] = s; rq[w] = sq; }
    __syncthreads();
    if (tid == 0) {
        float S = 0.f, Q = 0.f;
#pragma unroll
        for (int i = 0; i < 8; ++i) { S += rs[i]; Q += rq[i]; }
        float mu = S / 6272.f;
        float v  = Q / 6272.f - mu * mu;
        smu = mu; srstd = rsqrtf(v + 1e-5f);
    }
    __syncthreads();
    float mu = smu, rstd = srstd;

    for (int u = tid; u < 2048; u += 512) {
        int l = u & 63, q = (u >> 6) & 3, ct = u >> 8;
        int c0 = ct * 16 + ((l >> 4) << 2);
        int k  = q * 16 + (l & 15);
        ushort4 o;
        if (k < 49) {
            o.x = f2bf(tanhf((F0[c0+0][k] - mu) * rstd * lnw[(c0+0)*49+k] + lnb[(c0+0)*49+k]));
            o.y = f2bf(tanhf((F0[c0+1][k] - mu) * rstd * lnw[(c0+1)*49+k] + lnb[(c0+1)*49+k]));
            o.z = f2bf(tanhf((F0[c0+2][k] - mu) * rstd * lnw[(c0+2)*49+k] + lnb[(c0+2)*49+k]));
            o.w = f2bf(tanhf((F0[c0+3][k] - mu) * rstd * lnw[(c0+3)*49+k] + lnb[(c0+3)*49+k]));
        } else { o.x = o.y = o.z = o.w = 0; }
        ((ushort4*)GF)[(((size_t)b * 8 + ct) * 4 + q) * 64 + l] = o;
    }
}

// ---------------------------------------------------------------------------
// 6) fusion1 (fragment GEMM, fp32 out + bias; corrected epilogue map).
// ---------------------------------------------------------------------------
template <int KT>
__global__ __launch_bounds__(256) void fusion_frag_k(
    const u16* __restrict__ AF, const u16* __restrict__ WF,
    float* __restrict__ Cout, const float* __restrict__ bias)
{
    int tid  = threadIdx.x;
    int lane = tid & 63;
    int w    = tid >> 6;
    int b    = blockIdx.y;
    int t    = blockIdx.x * 4 + w;

    const bf16x4* Ab = (const bf16x4*)AF + (size_t)b * (KT * 256) + lane;
    const bf16x4* Bw = (const bf16x4*)WF + (size_t)t * (KT * 64) + lane;

    f32x4 acc[4];
#pragma unroll
    for (int q = 0; q < 4; ++q) acc[q] = (f32x4)0.f;

#pragma unroll
    for (int ct = 0; ct < KT; ++ct) {
        bf16x4 wv = Bw[ct * 64];
        bf16x4 a0 = Ab[(ct * 4 + 0) * 64];
        bf16x4 a1 = Ab[(ct * 4 + 1) * 64];
        bf16x4 a2 = Ab[(ct * 4 + 2) * 64];
        bf16x4 a3 = Ab[(ct * 4 + 3) * 64];
        acc[0] = mfma16x16(a0, wv, acc[0]);
        acc[1] = mfma16x16(a1, wv, acc[1]);
        acc[2] = mfma16x16(a2, wv, acc[2]);
        acc[3] = mfma16x16(a3, wv, acc[3]);
    }

    int c = t * 16 + (lane & 15);
    float bb = bias[c];
    float* op = Cout + (size_t)c * NB + b * 49;
    int g4 = (lane >> 4) << 2;
#pragma unroll
    for (int q = 0; q < 4; ++q) {
#pragma unroll
        for (int r = 0; r < 4; ++r) {
            int p = q * 16 + g4 + r;
            if (p < 49) op[p] = acc[q][r] + bb;
        }
    }
}

// ---------------------------------------------------------------------------
// 7) dynamic depthwise 7x7 conv (round-8/13 best: wave-per-plane, SGPR
//    weights, skewed LDS staging).
// ---------------------------------------------------------------------------
#define PLS 1256
__global__ __launch_bounds__(256) void dwconv_k(
    const float* __restrict__ x, const float* __restrict__ KernT,
    float* __restrict__ out)
{
    __shared__ float xs[4 * PLS];
    int tid  = threadIdx.x;
    int lane = tid & 63;
    int wid  = tid >> 6;
    int P    = blockIdx.x * 4 + wid;
    int b = P >> 9, c = P & 511;
    float* pl = &xs[wid * PLS];

    float4* plf = (float4*)pl;
#pragma unroll
    for (int r = 0; r < 5; ++r) {
        int l = lane + 64 * r;
        if (l < PLS / 4) plf[l] = float4{0.f, 0.f, 0.f, 0.f};
    }

    float wvl = 0.f;
    if (lane < 49) wvl = KernT[(size_t)c * NB + b * 49 + lane];
    int wvi = __float_as_int(wvl);
    float w[49];
#pragma unroll
    for (int i = 0; i < 49; ++i)
        w[i] = __int_as_float(__builtin_amdgcn_readlane(wvi, i));

    const float* src = x + (size_t)P * 784;
#pragma unroll
    for (int r = 0; r < 4; ++r) {
        int q = lane + 64 * r;
        if (q < 196) {
            int y = q / 7, xq = 4 * (q % 7);
            int R = y + 3;
            *(float4*)&pl[R * 36 + (((R >> 2) & 7) << 2) + xq + 4] =
                *(const float4*)(src + y * 28 + xq);
        }
    }

    if (lane >= 49) return;
    int ty = lane / 7, gx = lane - ty * 7;
    int y0 = 4 * ty, x0 = 4 * gx;
    float acc[4][4] = {};

#pragma unroll
    for (int yy = 0; yy < 10; ++yy) {
        int R = y0 + yy;
        const float* rp = &pl[R * 36 + (((R >> 2) & 7) << 2) + x0];
        float4 fa = *(const float4*)(rp);
        float4 fb = *(const float4*)(rp + 4);
        float4 fc = *(const float4*)(rp + 8);
        float f[12] = {fa.x, fa.y, fa.z, fa.w, fb.x, fb.y, fb.z, fb.w,
                       fc.x, fc.y, fc.z, fc.w};
#pragma unroll
        for (int j = 0; j < 4; ++j) {
            int dy = yy - j;
            if (dy < 0 || dy > 6) continue;
#pragma unroll
            for (int dx = 0; dx < 7; ++dx) {
                float wv = w[dy * 7 + dx];
                acc[j][0] = fmaf(wv, f[dx + 1], acc[j][0]);
                acc[j][1] = fmaf(wv, f[dx + 2], acc[j][1]);
                acc[j][2] = fmaf(wv, f[dx + 3], acc[j][2]);
                acc[j][3] = fmaf(wv, f[dx + 4], acc[j][3]);
            }
        }
    }

    float* op = out + (size_t)P * 784;
#pragma unroll
    for (int j = 0; j < 4; ++j) {
        float4 o4 = {acc[j][0], acc[j][1], acc[j][2], acc[j][3]};
        *(float4*)(op + (y0 + j) * 28 + x0) = o4;
    }
}

// ---------------------------------------------------------------------------
extern "C" void kernel_launch(void* const* d_in, const int* in_sizes, int n_in,
                              void* d_out, int out_size, void* d_ws, size_t ws_size,
                              hipStream_t stream)
{
    const float* x     = (const float*)d_in[0];
    const float* bng   = (const float*)d_in[1];
    const float* bnb   = (const float*)d_in[2];
    const float* bnm   = (const float*)d_in[3];
    const float* bnv   = (const float*)d_in[4];
    const float* Wq    = (const float*)d_in[5];
    const float* Wk    = (const float*)d_in[6];
    const float* Wkern = (const float*)d_in[7];
    const float* Wf0   = (const float*)d_in[8];
    const float* bf0   = (const float*)d_in[9];
    const float* lnw   = (const float*)d_in[10];
    const float* lnb   = (const float*)d_in[11];
    const float* Wf1   = (const float*)d_in[12];
    const float* bf1   = (const float*)d_in[13];
    float* out = (float*)d_out;
    float* ws  = (float*)d_ws;

    // workspace (float-equiv offsets), peak 5,834,752 f = 23.3 MB
    u16* pfF    = (u16*)(ws + 0);            // [0 .. 1,048,576)
    u16* VF     = (u16*)(ws + 1048576);      // [1,048,576 .. 2,097,152)
    u16* WqF    = (u16*)(ws + 2097152);      // [2,097,152 .. 2,228,224)
    u16* WkF    = (u16*)(ws + 2228224);      // [2,228,224 .. 2,359,296)
    u16* Wf0F   = (u16*)(ws + 2359296);      // [2,359,296 .. 2,392,064)
    u16* Wf1F   = (u16*)(ws + 2392064);      // [2,392,064 .. 2,424,832)
    u16* WkernF = (u16*)(ws + 2424832);      // [2,424,832 .. 2,426,880)
    u16* QF     = (u16*)(ws + 2426880);      // [2,426,880 .. 3,475,456)
    u16* KF     = (u16*)(ws + 3475456);      // [3,475,456 .. 4,524,032)
    u16* OtF    = (u16*)(ws + 4524032);      // [4,524,032 .. 5,572,608)
    u16* GF     = (u16*)(ws + 5572608);      // [5,572,608 .. 5,834,752)
    float* KernT = ws + 2426880;             // reuses QF+KF (dead after attn)

    repack_all_k<<<644, 256, 0, stream>>>(Wq, Wk, Wf0, Wf1, Wkern,
                                          WqF, WkF, Wf0F, Wf1F, WkernF);
    prep_k<<<256, 256, 0, stream>>>(x, bng, bnb, bnm, bnv, WkernF, pfF, VF);
    gemm_qk_k<<<dim3(8, 64, 2), 256, 0, stream>>>(pfF, WqF, WkF, QF, KF);
    attn_mfma_k<<<dim3(8, 64), 256, 0, stream>>>(QF, KF, VF, OtF);
    f0ln_k<<<64, 512, 0, stream>>>(OtF, Wf0F, bf0, lnw, lnb, GF);
    fusion_frag_k<8><<<dim3(8, 64), 256, 0, stream>>>(GF, Wf1F, KernT, bf1);
    dwconv_k<<<8192, 256, 0, stream>>>(x, KernT, out);
}